// Round 2
// baseline (672.698 us; speedup 1.0000x reference)
//
#include <hip/hip_runtime.h>

#define NTOK  16384
#define INF   2048
#define OUTF  2048
#define RANK  45
#define GTOK  8

// ---------------- Kernel A: t = x @ shared_in  [N,2048]@[2048,45] ----------------
// 256 blocks x 256 thr; block = 64 rows, 4-way K split (wave-uniform -> s_load si)
__global__ __launch_bounds__(256) void t_gemm_kernel(
    const float* __restrict__ x, const float* __restrict__ si, float* __restrict__ t)
{
    __shared__ float P_lds[4][64][RANK];          // 46 KB, stride 45 (odd) -> conflict-free
    const int lane = threadIdx.x & 63;
    const int ks   = __builtin_amdgcn_readfirstlane(threadIdx.x >> 6);  // wave-uniform
    const int row  = blockIdx.x * 64 + lane;
    const float* __restrict__ xr = x + (size_t)row * INF + ks * 512;

    float P[RANK];
#pragma unroll
    for (int r = 0; r < RANK; ++r) P[r] = 0.f;

    for (int k = 0; k < 512; k += 4) {
        const float4 xv = *(const float4*)(xr + k);
        const float* __restrict__ s0 = si + (size_t)(ks * 512 + k) * RANK;  // uniform -> SGPR
#pragma unroll
        for (int r = 0; r < RANK; ++r) {
            P[r] += xv.x * s0[r];
            P[r] += xv.y * s0[RANK + r];
            P[r] += xv.z * s0[2 * RANK + r];
            P[r] += xv.w * s0[3 * RANK + r];
        }
    }
#pragma unroll
    for (int r = 0; r < RANK; ++r) P_lds[ks][lane][r] = P[r];
    __syncthreads();
    for (int idx = threadIdx.x; idx < 64 * RANK; idx += 256) {
        const int rw = idx / RANK;
        const int rr = idx - rw * RANK;
        t[(size_t)(blockIdx.x * 64 + rw) * RANK + rr] =
            P_lds[0][rw][rr] + P_lds[1][rw][rr] + P_lds[2][rw][rr] + P_lds[3][rw][rr];
    }
}

// ---------------- Kernel B: out = t@so + gain * vec(V x U^T) ----------------
// block = GTOK tokens, 256 thr. acc[g][j] fully static-indexed (registers).
// col = (dgrp+16*jd)*32 + c0 + 16*jc ; d = col>>5, c = col&31
__global__ __launch_bounds__(256) void fused_kernel(
    const float* __restrict__ x, const int* __restrict__ rid_p,
    const float* __restrict__ so, const float* __restrict__ rU,
    const float* __restrict__ rV, const float* __restrict__ gains,
    const float* __restrict__ t, float* __restrict__ out)
{
    __shared__ __align__(16) float x_lds[INF];        // 8 KB
    __shared__ __align__(16) float xu_t[32][68];      // [c][b] padded (8.7 KB)
    __shared__ __align__(16) float U_t[32][33];       // [a][c] transposed (4.2 KB)
    __shared__ __align__(16) float V_lds[64][68];     // [d][b] padded (17.4 KB)
    __shared__ float t_lds[GTOK][RANK + 1];

    const int tid  = threadIdx.x;
    const int n0   = blockIdx.x * GTOK;
    const int c0   = tid & 15;
    const int dgrp = tid >> 4;        // 0..15
    const int cx   = tid & 31;
    const int bg   = tid >> 5;        // 0..7

    for (int i = tid; i < GTOK * RANK; i += 256) {
        const int g = i / RANK, r = i - g * RANK;
        t_lds[g][r] = t[(size_t)(n0 + g) * RANK + r];
    }

    float acc[GTOK][8];
#pragma unroll
    for (int g = 0; g < GTOK; ++g)
#pragma unroll
        for (int j = 0; j < 8; ++j) acc[g][j] = 0.f;

    __syncthreads();

    // ---- base: acc[g][j] += sum_k t[g][k] * so[k][col_j]  (so L2-resident)
    for (int k = 0; k < RANK; ++k) {
        float sv[8];
#pragma unroll
        for (int jd = 0; jd < 4; ++jd)
#pragma unroll
            for (int jc = 0; jc < 2; ++jc)
                sv[jd * 2 + jc] = so[(size_t)k * OUTF + (dgrp + 16 * jd) * 32 + c0 + 16 * jc];
#pragma unroll
        for (int g = 0; g < GTOK; ++g) {
            const float tv = t_lds[g][k];
#pragma unroll
            for (int j = 0; j < 8; ++j) acc[g][j] += tv * sv[j];
        }
    }

    // ---- adapter, one token at a time (g unrolled so acc stays in regs)
#pragma unroll
    for (int g = 0; g < GTOK; ++g) {
        const int n = n0 + g;
        const int rid = rid_p[n];                 // block-uniform -> s_load
        const float gain = gains[rid];
        const float* __restrict__ xr = x + (size_t)n * INF;
        const float* __restrict__ Ur = rU + (size_t)rid * (32 * 32);
        const float* __restrict__ Vr = rV + (size_t)rid * (64 * 64);

        __syncthreads();   // previous iteration's readers done
        ((float4*)x_lds)[tid]       = ((const float4*)xr)[tid];
        ((float4*)x_lds)[tid + 256] = ((const float4*)xr)[tid + 256];
#pragma unroll
        for (int i = 0; i < 4; ++i) {
            const int ii = tid + i * 256;         // 0..1023
            U_t[ii & 31][ii >> 5] = Ur[ii];       // U_t[a][c] = U[c][a]
        }
#pragma unroll
        for (int i = 0; i < 4; ++i) {
            const int i4 = tid + i * 256;         // float4 idx 0..1023
            const int d = i4 >> 4;
            const int b = (i4 & 15) * 4;
            *(float4*)&V_lds[d][b] = ((const float4*)Vr)[i4];
        }
        __syncthreads();

        // xu[b][cx] = sum_a x[b*32+a] * U[cx][a],  b = bg*8 + jj
        float xacc[8];
#pragma unroll
        for (int jj = 0; jj < 8; ++jj) xacc[jj] = 0.f;
        for (int a = 0; a < 32; a += 4) {
            const float u0 = U_t[a][cx], u1 = U_t[a + 1][cx];
            const float u2 = U_t[a + 2][cx], u3 = U_t[a + 3][cx];
#pragma unroll
            for (int jj = 0; jj < 8; ++jj) {
                const float4 xv = *(const float4*)&x_lds[(bg * 8 + jj) * 32 + a];  // broadcast
                xacc[jj] += xv.x * u0 + xv.y * u1 + xv.z * u2 + xv.w * u3;
            }
        }
#pragma unroll
        for (int jj = 0; jj < 8; ++jj) xu_t[cx][bg * 8 + jj] = xacc[jj];
        __syncthreads();

        // vxu[d][c] = sum_b V[d][b] * xu[b][c]
        float vtmp[8];
#pragma unroll
        for (int j = 0; j < 8; ++j) vtmp[j] = 0.f;
        for (int b = 0; b < 64; b += 4) {
            const float4 xc0 = *(const float4*)&xu_t[c0][b];
            const float4 xc1 = *(const float4*)&xu_t[c0 + 16][b];
#pragma unroll
            for (int jd = 0; jd < 4; ++jd) {
                const float4 vv = *(const float4*)&V_lds[dgrp + 16 * jd][b];  // 4-addr bcast
                vtmp[jd * 2]     += vv.x * xc0.x + vv.y * xc0.y + vv.z * xc0.z + vv.w * xc0.w;
                vtmp[jd * 2 + 1] += vv.x * xc1.x + vv.y * xc1.y + vv.z * xc1.z + vv.w * xc1.w;
            }
        }
#pragma unroll
        for (int j = 0; j < 8; ++j) acc[g][j] += gain * vtmp[j];
    }

    // ---- store (16-lane contiguous 64B segments)
#pragma unroll
    for (int g = 0; g < GTOK; ++g) {
        float* __restrict__ orow = out + (size_t)(n0 + g) * OUTF;
#pragma unroll
        for (int jd = 0; jd < 4; ++jd)
#pragma unroll
            for (int jc = 0; jc < 2; ++jc)
                orow[(dgrp + 16 * jd) * 32 + c0 + 16 * jc] = acc[g][jd * 2 + jc];
    }
}

extern "C" void kernel_launch(void* const* d_in, const int* in_sizes, int n_in,
                              void* d_out, int out_size, void* d_ws, size_t ws_size,
                              hipStream_t stream) {
    const float* x   = (const float*)d_in[0];
    const int*   rid = (const int*)d_in[1];
    const float* si  = (const float*)d_in[2];
    const float* so  = (const float*)d_in[3];
    const float* rU  = (const float*)d_in[4];
    const float* rV  = (const float*)d_in[5];
    const float* rg  = (const float*)d_in[6];
    float* out = (float*)d_out;
    float* t   = (float*)d_ws;                    // needs N*45*4 = 2.95 MB scratch

    t_gemm_kernel<<<NTOK / 64, 256, 0, stream>>>(x, si, t);
    fused_kernel<<<NTOK / GTOK, 256, 0, stream>>>(x, rid, so, rU, rV, rg, t, out);
}